// Round 7
// baseline (243.312 us; speedup 1.0000x reference)
//
#include <hip/hip_runtime.h>

typedef __bf16 bf16x8 __attribute__((ext_vector_type(8)));
typedef float  f32x4  __attribute__((ext_vector_type(4)));

#define LOG2E 1.4426950408889634f

static __device__ __forceinline__ float fexp2(float x) { return __builtin_amdgcn_exp2f(x); }
static __device__ __forceinline__ float frcp(float x)  { return __builtin_amdgcn_rcpf(x); }
static __device__ __forceinline__ float fsigmoid(float x) { return frcp(1.0f + fexp2(-LOG2E * x)); }
static __device__ __forceinline__ float ftanh(float x)    { return 2.0f * frcp(1.0f + fexp2(-2.0f * LOG2E * x)) - 1.0f; }

// ---------------------------------------------------------------------------
// Prep: pack 4 [512x512] fp32 weights into bf16 16x16x32-B-fragment order.
// Wp[(((g*32+cn)*16+ks)*64 + lane)*8 + e] = W_g[cn*16+(lane&15)][ks*32+(lane>>4)*8+e]
// ---------------------------------------------------------------------------
__global__ __launch_bounds__(256) void wpack(const float* __restrict__ Wf,
                                             const float* __restrict__ Wi,
                                             const float* __restrict__ Wg,
                                             const float* __restrict__ Wo,
                                             __bf16* __restrict__ Wp)
{
    int idx = blockIdx.x * 256 + threadIdx.x;      // [0, 131072)
    int kg  = idx & 63;                            // k-group of 8
    int j   = (idx >> 6) & 511;                    // weight row = output col
    int g   = idx >> 15;
    const float* src = (g == 0) ? Wf : (g == 1) ? Wi : (g == 2) ? Wg : Wo;
    const float4* s4 = (const float4*)(src + j * 512 + kg * 8);
    float4 v0 = s4[0], v1 = s4[1];
    bf16x8 o;
    o[0] = (__bf16)v0.x; o[1] = (__bf16)v0.y; o[2] = (__bf16)v0.z; o[3] = (__bf16)v0.w;
    o[4] = (__bf16)v1.x; o[5] = (__bf16)v1.y; o[6] = (__bf16)v1.z; o[7] = (__bf16)v1.w;
    int cn = j >> 4;                               // 16-col group
    int ks = kg >> 2;                              // K=32 step
    int lt = (j & 15) + (kg & 3) * 16;             // lane slot
    size_t dst = ((size_t)(((g * 32 + cn) * 16 + ks) * 64 + lt)) * 8;
    *(bf16x8*)(Wp + dst) = o;
}

// ---------------------------------------------------------------------------
// zpack: z = x + stm -> bf16, written to d_ws in the EXACT byte order of the
// (verified) per-tile LDS fragment image, so lstm_main can DMA it linearly.
// Tile = 128 rows = 128 KiB; chunk c (1 KiB) = (rb = c>>5, kk = c&31);
// slot s holds z[rb*32 + ((s^(kk&7))&31)][(2kk+(s>>5))*8 .. +8].
// Writes: lane-linear 1 KiB per wave-chunk. Reads: 64-B granules (lane pairs
// s, s+32 read contiguous 64 B of the same row).
// ---------------------------------------------------------------------------
__global__ __launch_bounds__(512) void zpack(const float* __restrict__ x,
                                             const float* __restrict__ s,
                                             __bf16* __restrict__ zf)
{
    const int tid  = threadIdx.x;
    const int lane = tid & 63;
    const int wv   = tid >> 6;
    const size_t tile = blockIdx.x;
    const size_t row0 = tile * 128;
    char* dstb = (char*)zf + tile * 131072;

    #pragma unroll 4
    for (int i = 0; i < 16; ++i) {
        int c   = wv * 16 + i;
        int rb  = c >> 5, kk = c & 31;
        int rl  = rb * 32 + ((lane ^ (kk & 7)) & 31);
        int kg  = 2 * kk + (lane >> 5);
        size_t off = (row0 + rl) * 512 + kg * 8;
        float4 a0 = *(const float4*)(x + off);
        float4 a1 = *(const float4*)(x + off + 4);
        float4 b0 = *(const float4*)(s + off);
        float4 b1 = *(const float4*)(s + off + 4);
        bf16x8 p;
        p[0] = (__bf16)(a0.x + b0.x); p[1] = (__bf16)(a0.y + b0.y);
        p[2] = (__bf16)(a0.z + b0.z); p[3] = (__bf16)(a0.w + b0.w);
        p[4] = (__bf16)(a1.x + b1.x); p[5] = (__bf16)(a1.y + b1.y);
        p[6] = (__bf16)(a1.z + b1.z); p[7] = (__bf16)(a1.w + b1.w);
        *(bf16x8*)(dstb + c * 1024 + lane * 16) = p;
    }
}

// ---------------------------------------------------------------------------
// Main GEMM kernel. Block: 512 thr (8 waves), BM=128 rows, 128 KiB LDS.
// Phase 0 is now a pure linear DMA (global_load_lds) of the pre-packed tile.
// K-loop / A-read offsets / epilogue identical to the verified round-6 code.
// ---------------------------------------------------------------------------
__global__ __launch_bounds__(512, 2) void lstm_main(
    const __bf16* __restrict__ zf,
    const __bf16* __restrict__ Wp,
    const float* __restrict__ bfv, const float* __restrict__ biv,
    const float* __restrict__ bgv, const float* __restrict__ bov,
    float* __restrict__ out)
{
    __shared__ unsigned char zs[131072];           // 128 rows x 512 k, frag image
    const int tid  = threadIdx.x;
    const int lane = tid & 63;
    const int wv   = tid >> 6;                     // 0..7
    const int l15  = lane & 15;
    const int lq   = lane >> 4;                    // 0..3
    const int row0 = blockIdx.x * 128;

    // ---- phase 0: linear DMA of the 128 KiB tile image into LDS ----
    {
        const char* srcb = (const char*)zf + (size_t)blockIdx.x * 131072 + (size_t)lane * 16;
        #pragma unroll
        for (int i = 0; i < 16; ++i) {
            int c = wv * 16 + i;
            __builtin_amdgcn_global_load_lds(
                (const __attribute__((address_space(1))) void*)(srcb + c * 1024),
                (__attribute__((address_space(3))) void*)(zs + c * 1024),
                16, 0, 0);
        }
    }
    asm volatile("s_waitcnt vmcnt(0)");
    __syncthreads();                               // only barrier

    // A-read (16x16x32 frag): row = m*16+l15, k = ks*32+lq*8
    // kk = 2ks+(lq>>1), slot = (l15 + (m&1)*16 + (lq&1)*32) ^ (kk&7)
    const int kkoff = lq >> 1;                     // 0/1
    const int s0    = l15 + (lq & 1) * 32;         // bit4 clear
    const int koffb = kkoff << 10;

    // ---- phase 1: column loop, no barriers ----
    for (int ci = 0; ci < 4; ++ci) {
        const int cn   = ci * 8 + wv;              // 16-col group [0,32)
        const int colj = cn * 16 + l15;

        const __bf16* bp0 = Wp + ((size_t)((  0 + cn) * 16)) * 512 + lane * 8;
        const __bf16* bp1 = Wp + ((size_t)(( 32 + cn) * 16)) * 512 + lane * 8;
        const __bf16* bp2 = Wp + ((size_t)(( 64 + cn) * 16)) * 512 + lane * 8;
        const __bf16* bp3 = Wp + ((size_t)(( 96 + cn) * 16)) * 512 + lane * 8;

        float bias0 = bfv[colj], bias1 = biv[colj], bias2 = bgv[colj], bias3 = bov[colj];
        f32x4 acc[8][4];                           // [m][gate] = 128 regs
        #pragma unroll
        for (int m = 0; m < 8; ++m) {
            #pragma unroll
            for (int r = 0; r < 4; ++r) {
                acc[m][0][r] = bias0; acc[m][1][r] = bias1;
                acc[m][2][r] = bias2; acc[m][3][r] = bias3;
            }
        }

        #pragma unroll 2
        for (int ks = 0; ks < 16; ++ks) {
            const int kk7 = ((2 * ks) & 7) | kkoff;
            const int t0  = ((s0 ^ kk7) << 4) + ks * 2048 + koffb;
            bf16x8 b0 = *(const bf16x8*)(bp0 + ks * 512);
            bf16x8 b1 = *(const bf16x8*)(bp1 + ks * 512);
            bf16x8 b2 = *(const bf16x8*)(bp2 + ks * 512);
            bf16x8 b3 = *(const bf16x8*)(bp3 + ks * 512);
            bf16x8 a[8];
            #pragma unroll
            for (int m = 0; m < 8; ++m)
                a[m] = *(const bf16x8*)(zs + (m >> 1) * 32768 + (m & 1) * 256 + t0);
            #pragma unroll
            for (int m = 0; m < 8; ++m) {
                acc[m][0] = __builtin_amdgcn_mfma_f32_16x16x32_bf16(a[m], b0, acc[m][0], 0, 0, 0);
                acc[m][1] = __builtin_amdgcn_mfma_f32_16x16x32_bf16(a[m], b1, acc[m][1], 0, 0, 0);
                acc[m][2] = __builtin_amdgcn_mfma_f32_16x16x32_bf16(a[m], b2, acc[m][2], 0, 0, 0);
                acc[m][3] = __builtin_amdgcn_mfma_f32_16x16x32_bf16(a[m], b3, acc[m][3], 0, 0, 0);
            }
        }

        // ---- epilogue: 16x16 C/D layout col=l&15, row=lq*4+r ----
        #pragma unroll
        for (int m = 0; m < 8; ++m) {
            #pragma unroll
            for (int r = 0; r < 4; ++r) {
                float F = acc[m][0][r], I = acc[m][1][r];
                float G = acc[m][2][r], O = acc[m][3][r];
                float c = fsigmoid(F) + fsigmoid(I) * ftanh(G);
                float h = ftanh(c) * fsigmoid(O);
                int row = row0 + m * 16 + lq * 4 + r;
                int o   = row * 512 + colj;
                out[o] = c;
                out[33554432 + o] = h;             // h plane at 65536*512
            }
        }
    }
}

extern "C" void kernel_launch(void* const* d_in, const int* in_sizes, int n_in,
                              void* d_out, int out_size, void* d_ws, size_t ws_size,
                              hipStream_t stream) {
    const float* xin = (const float*)d_in[0];
    const float* stm = (const float*)d_in[1];
    const float* Wf  = (const float*)d_in[2];
    const float* bf_ = (const float*)d_in[3];
    const float* Wi  = (const float*)d_in[4];
    const float* bi_ = (const float*)d_in[5];
    const float* Wg  = (const float*)d_in[6];
    const float* bg_ = (const float*)d_in[7];
    const float* Wo  = (const float*)d_in[8];
    const float* bo_ = (const float*)d_in[9];
    __bf16* Wp = (__bf16*)d_ws;                                  // 2 MiB packed weights
    __bf16* zf = (__bf16*)((char*)d_ws + (4 * 512 * 512 * 2));   // 64 MiB packed z

    wpack<<<512, 256, 0, stream>>>(Wf, Wi, Wg, Wo, Wp);
    zpack<<<512, 512, 0, stream>>>(xin, stm, zf);
    lstm_main<<<512, 512, 0, stream>>>(zf, Wp, bf_, bi_, bg_, bo_, (float*)d_out);
}

// Round 8
// 202.728 us; speedup vs baseline: 1.2002x; 1.2002x over previous
//
#include <hip/hip_runtime.h>

typedef __bf16 bf16x8 __attribute__((ext_vector_type(8)));
typedef float  f32x4  __attribute__((ext_vector_type(4)));

#define LOG2E 1.4426950408889634f

static __device__ __forceinline__ float fexp2(float x) { return __builtin_amdgcn_exp2f(x); }
static __device__ __forceinline__ float frcp(float x)  { return __builtin_amdgcn_rcpf(x); }
static __device__ __forceinline__ float fsigmoid(float x) { return frcp(1.0f + fexp2(-LOG2E * x)); }
static __device__ __forceinline__ float ftanh(float x)    { return 2.0f * frcp(1.0f + fexp2(-2.0f * LOG2E * x)) - 1.0f; }

// ---------------------------------------------------------------------------
// Prep: pack 4 [512x512] fp32 weights into bf16 16x16x32-B-fragment order.
// Wp[(((g*32+cn)*16+ks)*64 + lane)*8 + e] = W_g[cn*16+(lane&15)][ks*32+(lane>>4)*8+e]
// ---------------------------------------------------------------------------
__global__ __launch_bounds__(256) void wpack(const float* __restrict__ Wf,
                                             const float* __restrict__ Wi,
                                             const float* __restrict__ Wg,
                                             const float* __restrict__ Wo,
                                             __bf16* __restrict__ Wp)
{
    int idx = blockIdx.x * 256 + threadIdx.x;      // [0, 131072)
    int kg  = idx & 63;                            // k-group of 8
    int j   = (idx >> 6) & 511;                    // weight row = output col
    int g   = idx >> 15;
    const float* src = (g == 0) ? Wf : (g == 1) ? Wi : (g == 2) ? Wg : Wo;
    const float4* s4 = (const float4*)(src + j * 512 + kg * 8);
    float4 v0 = s4[0], v1 = s4[1];
    bf16x8 o;
    o[0] = (__bf16)v0.x; o[1] = (__bf16)v0.y; o[2] = (__bf16)v0.z; o[3] = (__bf16)v0.w;
    o[4] = (__bf16)v1.x; o[5] = (__bf16)v1.y; o[6] = (__bf16)v1.z; o[7] = (__bf16)v1.w;
    int cn = j >> 4;                               // 16-col group
    int ks = kg >> 2;                              // K=32 step
    int lt = (j & 15) + (kg & 3) * 16;             // lane slot
    size_t dst = ((size_t)(((g * 32 + cn) * 16 + ks) * 64 + lt)) * 8;
    *(bf16x8*)(Wp + dst) = o;
}

// ---------------------------------------------------------------------------
// Main fused kernel. Block: 1024 thr (16 waves), BM=128 rows, 128 KiB LDS,
// 1 block/CU, 4 waves/SIMD. Wave = (rh = wv>>3: 64-row half, cn8 = wv&7).
// Per wave: 64 rows x 16 cols x 4 gates -> acc = 4m x 4g x 4 = 64 regs.
// Twin waves (wv, wv+8) share B addresses -> L1 absorbs the duplication.
// ---------------------------------------------------------------------------
__global__ __launch_bounds__(1024, 4) void lstm_main(
    const float* __restrict__ xin, const float* __restrict__ stm,
    const __bf16* __restrict__ Wp,
    const float* __restrict__ bfv, const float* __restrict__ biv,
    const float* __restrict__ bgv, const float* __restrict__ bov,
    float* __restrict__ out)
{
    __shared__ unsigned char zs[131072];           // 128 rows x 512 k, bf16, frag order
    const int tid  = threadIdx.x;
    const int lane = tid & 63;
    const int wv   = tid >> 6;                     // 0..15
    const int cn8  = wv & 7;                       // column group within ci
    const int rh   = wv >> 3;                      // row half (0: rows 0-63, 1: 64-127)
    const int l15  = lane & 15;
    const int lq   = lane >> 4;                    // 0..3
    const int row0 = blockIdx.x * 128;

    // ---- phase 0: z = x + stm -> bf16 -> LDS in frag order (verified layout) ----
    {
        const float* xb = xin + (size_t)row0 * 512;
        const float* sb = stm + (size_t)row0 * 512;
        #pragma unroll
        for (int it = 0; it < 8; ++it) {
            int idx = it * 1024 + tid;             // [0, 8192): 128 rows x 64 kgroups
            int row = idx >> 6;
            int kg  = idx & 63;
            const float4* x4 = (const float4*)(xb + row * 512 + kg * 8);
            const float4* s4 = (const float4*)(sb + row * 512 + kg * 8);
            float4 a0 = x4[0], a1 = x4[1];
            float4 b0 = s4[0], b1 = s4[1];
            bf16x8 p;
            p[0] = (__bf16)(a0.x + b0.x); p[1] = (__bf16)(a0.y + b0.y);
            p[2] = (__bf16)(a0.z + b0.z); p[3] = (__bf16)(a0.w + b0.w);
            p[4] = (__bf16)(a1.x + b1.x); p[5] = (__bf16)(a1.y + b1.y);
            p[6] = (__bf16)(a1.z + b1.z); p[7] = (__bf16)(a1.w + b1.w);
            int rb   = row >> 5;                   // 0..3 chunk (32 KiB each)
            int kk   = kg >> 1;
            int slot = ((row & 31) + (kg & 1) * 32) ^ (kk & 7);
            *(bf16x8*)(zs + rb * 32768 + kk * 1024 + slot * 16) = p;
        }
    }
    __syncthreads();                               // only barrier

    // A-read (16x16x32 frag), global m = rh*4 + ml, row = m*16 + l15:
    // kk = 2ks+(lq>>1), slot = (l15 + (ml&1)*16 + (lq&1)*32) ^ (kk&7)
    // byte = rh*65536 + (ml>>1)*32768 + (ml&1)*256 + ((s0^kk7)<<4) + ks*2048 + koffb
    const int kkoff = lq >> 1;                     // 0/1
    const int s0    = l15 + (lq & 1) * 32;         // bit4 clear
    const int koffb = kkoff << 10;
    const int abase = rh * 65536;

    // ---- phase 1: column loop, no barriers ----
    for (int ci = 0; ci < 4; ++ci) {
        const int cn   = ci * 8 + cn8;             // 16-col group [0,32)
        const int colj = cn * 16 + l15;

        const __bf16* bp0 = Wp + ((size_t)((  0 + cn) * 16)) * 512 + lane * 8;
        const __bf16* bp1 = Wp + ((size_t)(( 32 + cn) * 16)) * 512 + lane * 8;
        const __bf16* bp2 = Wp + ((size_t)(( 64 + cn) * 16)) * 512 + lane * 8;
        const __bf16* bp3 = Wp + ((size_t)(( 96 + cn) * 16)) * 512 + lane * 8;

        float bias0 = bfv[colj], bias1 = biv[colj], bias2 = bgv[colj], bias3 = bov[colj];
        f32x4 acc[4][4];                           // [ml][gate] = 64 regs
        #pragma unroll
        for (int m = 0; m < 4; ++m) {
            #pragma unroll
            for (int r = 0; r < 4; ++r) {
                acc[m][0][r] = bias0; acc[m][1][r] = bias1;
                acc[m][2][r] = bias2; acc[m][3][r] = bias3;
            }
        }

        #pragma unroll 2
        for (int ks = 0; ks < 16; ++ks) {
            const int kk7 = ((2 * ks) & 7) | kkoff;
            const int t0  = abase + ((s0 ^ kk7) << 4) + ks * 2048 + koffb;
            bf16x8 b0 = *(const bf16x8*)(bp0 + ks * 512);
            bf16x8 b1 = *(const bf16x8*)(bp1 + ks * 512);
            bf16x8 b2 = *(const bf16x8*)(bp2 + ks * 512);
            bf16x8 b3 = *(const bf16x8*)(bp3 + ks * 512);
            bf16x8 a[4];
            #pragma unroll
            for (int m = 0; m < 4; ++m)
                a[m] = *(const bf16x8*)(zs + (m >> 1) * 32768 + (m & 1) * 256 + t0);
            #pragma unroll
            for (int m = 0; m < 4; ++m) {
                acc[m][0] = __builtin_amdgcn_mfma_f32_16x16x32_bf16(a[m], b0, acc[m][0], 0, 0, 0);
                acc[m][1] = __builtin_amdgcn_mfma_f32_16x16x32_bf16(a[m], b1, acc[m][1], 0, 0, 0);
                acc[m][2] = __builtin_amdgcn_mfma_f32_16x16x32_bf16(a[m], b2, acc[m][2], 0, 0, 0);
                acc[m][3] = __builtin_amdgcn_mfma_f32_16x16x32_bf16(a[m], b3, acc[m][3], 0, 0, 0);
            }
        }

        // ---- epilogue: 16x16 C/D layout col=l&15, row=lq*4+r ----
        #pragma unroll
        for (int m = 0; m < 4; ++m) {
            #pragma unroll
            for (int r = 0; r < 4; ++r) {
                float F = acc[m][0][r], I = acc[m][1][r];
                float G = acc[m][2][r], O = acc[m][3][r];
                float c = fsigmoid(F) + fsigmoid(I) * ftanh(G);
                float h = ftanh(c) * fsigmoid(O);
                int row = row0 + rh * 64 + m * 16 + lq * 4 + r;
                int o   = row * 512 + colj;
                out[o] = c;
                out[33554432 + o] = h;             // h plane at 65536*512
            }
        }
    }
}

extern "C" void kernel_launch(void* const* d_in, const int* in_sizes, int n_in,
                              void* d_out, int out_size, void* d_ws, size_t ws_size,
                              hipStream_t stream) {
    const float* xin = (const float*)d_in[0];
    const float* stm = (const float*)d_in[1];
    const float* Wf  = (const float*)d_in[2];
    const float* bf_ = (const float*)d_in[3];
    const float* Wi  = (const float*)d_in[4];
    const float* bi_ = (const float*)d_in[5];
    const float* Wg  = (const float*)d_in[6];
    const float* bg_ = (const float*)d_in[7];
    const float* Wo  = (const float*)d_in[8];
    const float* bo_ = (const float*)d_in[9];
    __bf16* Wp = (__bf16*)d_ws;                    // 2 MiB packed weights

    wpack<<<512, 256, 0, stream>>>(Wf, Wi, Wg, Wo, Wp);
    lstm_main<<<512, 1024, 0, stream>>>(xin, stm, Wp, bf_, bi_, bg_, bo_, (float*)d_out);
}